// Round 2
// baseline (326.526 us; speedup 1.0000x reference)
//
#include <hip/hip_runtime.h>

#define NUM_CODES 1024
#define EMBED_DIM 256
#define NPIX      32768      // 32 batches * 32*32
#define NELEM     8388608    // 32*256*32*32
#define PX        64         // pixels per block
#define KT        128        // codes per k-chunk
#define CT        16         // channels per LDS tile

// d_out layout (reference return order, flattened):
//   [0, 8388608)             z_q_ste  (fp32, [B,C,H,W])
//   8388608                  codebook_loss
//   8388609                  commitment_loss
//   [8388610, 8388610+32768) indices (as float)
#define LOSS_OFF 8388608
#define IDX_OFF  8388610

// ws layout: ws[0] = loss accumulator; ws[16..16+1024) = ||e_k||^2

__global__ void esq_kernel(const float* __restrict__ E, float* __restrict__ esq) {
    int w = threadIdx.x >> 6;
    int lane = threadIdx.x & 63;
    int k = blockIdx.x * 4 + w;
    const float* row = E + (size_t)k * EMBED_DIM;
    float s = 0.f;
    #pragma unroll
    for (int j = 0; j < EMBED_DIM; j += 64) { float v = row[j + lane]; s += v * v; }
    #pragma unroll
    for (int off = 32; off; off >>= 1) s += __shfl_down(s, off, 64);
    if (lane == 0) esq[k] = s;
}

__launch_bounds__(256, 2)
__global__ void vq_main(const float* __restrict__ z, const float* __restrict__ E,
                        const float* __restrict__ esq, float* __restrict__ out,
                        float* __restrict__ lossacc) {
    __shared__ float Zs[CT][PX];
    __shared__ float Es[CT][KT + 4];   // pad to 132 floats: conflict-free transposed store
    __shared__ float rd[16][PX];
    __shared__ int   rk[16][PX];
    __shared__ int   bkf[PX];
    __shared__ float zsqs[PX];

    const int t  = threadIdx.x;
    const int tx = t & 15;        // pixel group: px = tx*4 .. tx*4+3
    const int ty = t >> 4;        // code group: k = ty*4..+3 and 64+ty*4..+3
    const int px_base = blockIdx.x * PX;
    const int b  = px_base >> 10;
    const int hw = px_base & 1023;
    const float* zb = z + ((size_t)b << 18) + hw;   // z[b, :, hw..hw+63], stride 1024 per c

    // ---- prologue: per-pixel ||z||^2 (needed to replicate reference's fp32
    // rounding of dist = (z^2 + e^2) - 2 z.e — quantization at ~256 creates
    // the ties np.argmin breaks by first index) ----
    {
        int px = t & 63, g = t >> 6;           // g in 0..3, 64 channels each
        const float* zp = zb + px;
        float s = 0.f;
        #pragma unroll 8
        for (int r = 0; r < 64; ++r) {
            float v = zp[(size_t)(g * 64 + r) * 1024];
            s += v * v;
        }
        rd[g][px] = s;
    }
    __syncthreads();
    if (t < PX)
        zsqs[t] = (rd[0][t] + rd[1][t]) + (rd[2][t] + rd[3][t]);
    __syncthreads();
    float zsqv[4];
    #pragma unroll
    for (int i = 0; i < 4; ++i) zsqv[i] = zsqs[tx * 4 + i];

    float bd[4]; int bk[4];
    #pragma unroll
    for (int i = 0; i < 4; ++i) { bd[i] = 3.4e38f; bk[i] = 0; }

    for (int kb = 0; kb < NUM_CODES; kb += KT) {
        float acc[4][8];
        #pragma unroll
        for (int i = 0; i < 4; ++i)
            #pragma unroll
            for (int j = 0; j < 8; ++j) acc[i][j] = 0.f;

        for (int cb = 0; cb < EMBED_DIM; cb += CT) {
            __syncthreads();  // previous tile fully consumed
            {   // stage Z tile [CT][PX], coalesced float4
                int c = t >> 4, q = (t & 15) * 4;
                *(float4*)&Zs[c][q] = *(const float4*)&zb[(size_t)(cb + c) * 1024 + q];
            }
            {   // stage E tile transposed -> Es[c][k]
                int k = t & 127, ch = (t >> 7) * 8;
                const float* erow = E + (size_t)(kb + k) * EMBED_DIM + cb + ch;
                float4 a = *(const float4*)erow;
                float4 c4 = *(const float4*)(erow + 4);
                Es[ch + 0][k] = a.x;  Es[ch + 1][k] = a.y;
                Es[ch + 2][k] = a.z;  Es[ch + 3][k] = a.w;
                Es[ch + 4][k] = c4.x; Es[ch + 5][k] = c4.y;
                Es[ch + 6][k] = c4.z; Es[ch + 7][k] = c4.w;
            }
            __syncthreads();
            #pragma unroll
            for (int c = 0; c < CT; ++c) {
                float4 zv = *(float4*)&Zs[c][tx * 4];
                float4 ea = *(float4*)&Es[c][ty * 4];
                float4 eb = *(float4*)&Es[c][64 + ty * 4];
                float zr[4] = {zv.x, zv.y, zv.z, zv.w};
                float er[8] = {ea.x, ea.y, ea.z, ea.w, eb.x, eb.y, eb.z, eb.w};
                #pragma unroll
                for (int i = 0; i < 4; ++i)
                    #pragma unroll
                    for (int j = 0; j < 8; ++j)
                        acc[i][j] = fmaf(zr[i], er[j], acc[i][j]);
            }
        }
        // fold chunk into running argmin, replicating reference rounding:
        //   tmp = RN(zsq + esq);  d = RN(tmp - 2*acc)   (fmaf: product exact)
        #pragma unroll
        for (int j = 0; j < 8; ++j) {
            int kl = (j < 4) ? (ty * 4 + j) : (64 + ty * 4 + (j - 4));
            int kg = kb + kl;
            float eq = esq[kg];
            #pragma unroll
            for (int i = 0; i < 4; ++i) {
                float tmp = zsqv[i] + eq;
                float d = fmaf(-2.f, acc[i][j], tmp);
                if (d < bd[i]) { bd[i] = d; bk[i] = kg; }
            }
        }
    }

    // cross-thread (ty) reduction per pixel, lexicographic (d, k)
    __syncthreads();  // Zs/Es done; reuse rd/rk
    #pragma unroll
    for (int i = 0; i < 4; ++i) { rd[ty][tx * 4 + i] = bd[i]; rk[ty][tx * 4 + i] = bk[i]; }
    __syncthreads();
    if (t < PX) {
        float d = rd[0][t]; int k = rk[0][t];
        #pragma unroll
        for (int y = 1; y < 16; ++y) {
            float d2 = rd[y][t]; int k2 = rk[y][t];
            if (d2 < d || (d2 == d && k2 < k)) { d = d2; k = k2; }
        }
        bkf[t] = k;
        out[IDX_OFF + px_base + t] = (float)k;
        // d now includes ||z||^2: it is exactly ||z - e_k*||^2 for this pixel
        float s = d;
        #pragma unroll
        for (int off = 32; off; off >>= 1) s += __shfl_down(s, off, 64);
        if (t == 0) atomicAdd(lossacc, s);
    }
    __syncthreads();
    // gather chosen embedding rows, write z_q (coalesced in px)
    {
        int px = t & 63, cr = t >> 6;
        int myk = bkf[px];
        float* ob = out + ((size_t)b << 18) + hw + px;
        const float* er = E + (size_t)myk * EMBED_DIM;
        #pragma unroll 4
        for (int r = 0; r < 64; ++r) {
            int c = cr * 64 + r;
            ob[(size_t)c * 1024] = er[c];
        }
    }
}

__global__ void fin_kernel(const float* __restrict__ ws0, float* __restrict__ out) {
    float L = ws0[0] / (float)NELEM;
    out[LOSS_OFF]     = L;
    out[LOSS_OFF + 1] = 0.25f * L;
}

extern "C" void kernel_launch(void* const* d_in, const int* in_sizes, int n_in,
                              void* d_out, int out_size, void* d_ws, size_t ws_size,
                              hipStream_t stream) {
    const float* z = (const float*)d_in[0];           // [32,256,32,32]
    const float* E = (const float*)d_in[1];           // [1024,256]
    float* out = (float*)d_out;
    float* ws  = (float*)d_ws;

    hipMemsetAsync(d_ws, 0, 64, stream);              // zero loss accumulator
    esq_kernel<<<NUM_CODES / 4, 256, 0, stream>>>(E, ws + 16);
    vq_main<<<NPIX / PX, 256, 0, stream>>>(z, E, ws + 16, out, ws);
    fin_kernel<<<1, 1, 0, stream>>>(ws, out);
}